// Round 14
// baseline (516.342 us; speedup 1.0000x reference)
//
#include <hip/hip_runtime.h>

#define EPSF 1e-5f

typedef _Float16 h2f  __attribute__((ext_vector_type(2)));
typedef _Float16 h8   __attribute__((ext_vector_type(8)));
typedef float    f32x4 __attribute__((ext_vector_type(4)));

#if defined(__has_builtin)
#if __has_builtin(__builtin_amdgcn_fdot2)
#define HAVE_FDOT2 1
#endif
#endif

__device__ __forceinline__ float fsig(float x){ return 1.0f/(1.0f+__expf(-x)); }
__device__ __forceinline__ float ftanh(float x){
  float e = __expf(2.f*x);
  float r = (e-1.f)/(e+1.f);
  return (x > 15.f) ? 1.f : ((x < -15.f) ? -1.f : r);
}
__device__ __forceinline__ int pkf(float lo, float hi){
  return __builtin_bit_cast(int, __builtin_amdgcn_cvt_pkrtz(lo, hi));
}
__device__ __forceinline__ int4 mk4(const float* p){
  return make_int4(pkf(p[0],p[1]),pkf(p[2],p[3]),pkf(p[4],p[5]),pkf(p[6],p[7]));
}
__device__ __forceinline__ float dot2(int w, int x, float acc){
#ifdef HAVE_FDOT2
  return __builtin_amdgcn_fdot2(__builtin_bit_cast(h2f, w),
                                __builtin_bit_cast(h2f, x), acc, false);
#else
  h2f a = __builtin_bit_cast(h2f, w), b = __builtin_bit_cast(h2f, x);
  return acc + (float)a[0]*(float)b[0] + (float)a[1]*(float)b[1];
#endif
}
__device__ __forceinline__ int rl_i(int v, int l){ return __builtin_amdgcn_readlane(v, l); }
// light barrier: order LDS only; global loads/stores stay in flight
#define BAR() do{ asm volatile("s_waitcnt lgkmcnt(0)" ::: "memory"); __builtin_amdgcn_s_barrier(); }while(0)

// ---------------------------------------------------------------------------
// Kernel 1: msum[t] = sum_{b,n} masks[b,t,n] + EPS   (one block per t)
// ---------------------------------------------------------------------------
__global__ void msum_kernel(const float* __restrict__ masks, float* __restrict__ msum){
  const int t   = blockIdx.x;
  const int tid = threadIdx.x;
  const int b0  = tid >> 3;
  const int n4  = (tid & 7) << 2;
  float s = 0.f;
  #pragma unroll 4
  for (int i = 0; i < 32; ++i) {
    const int b = b0 + (i << 5);
    const float4 v = *reinterpret_cast<const float4*>(masks + ((size_t)b*256 + t)*32 + n4);
    s += v.x + v.y + v.z + v.w;
  }
  __shared__ float red[256];
  red[tid] = s; __syncthreads();
  for (int off = 128; off > 0; off >>= 1) {
    if (tid < off) red[tid] += red[tid + off];
    __syncthreads();
  }
  if (tid == 0) msum[t] = red[0] + EPSF;
}

// ---------------------------------------------------------------------------
// Kernel 2: persistent RNN. 256 blocks x 512 threads, 4 batch elems / block.
// PAIR-SPACE chain (lane l owns features 2l,2l+1; h/c pairs on lanes 0-31):
// every packed broadcast word (dw/hw/xcw/gxw/mw/ccw) is an IN-LANE cvt_pkrtz
// of two registers -- ZERO cross-lane shuffles on the chain critical path
// (r12 had 5 serial ds_bpermute pack stages ~120cyc each). Chain weights in
// conflict-free group-major LDS (data-independent reads -> prefetchable).
// Skeleton = r12: chains waves 0-3, monolithic MFMA gate GEMM, 2 barriers.
// ---------------------------------------------------------------------------
__global__ __launch_bounds__(512, 1) void rits_kernel(
  const float* __restrict__ values, const float* __restrict__ masks,
  const float* __restrict__ deltas, const float* __restrict__ labels,
  const float* __restrict__ is_train,
  const float* __restrict__ td_h_W, const float* __restrict__ td_h_b,
  const float* __restrict__ td_x_W, const float* __restrict__ td_x_b,
  const float* __restrict__ hist_W, const float* __restrict__ hist_b,
  const float* __restrict__ feat_W, const float* __restrict__ feat_b,
  const float* __restrict__ wc_W,  const float* __restrict__ wc_b,
  const float* __restrict__ W_ih,  const float* __restrict__ W_hh,
  const float* __restrict__ b_ih,  const float* __restrict__ b_hh,
  const float* __restrict__ out_W, const float* __restrict__ out_b,
  const float* __restrict__ msum,
  float* __restrict__ xl_acc, float* __restrict__ bce_acc,
  float* __restrict__ predictions, float* __restrict__ imps)
{
  // group-major packed weights, row-pair interleaved:
  // pkB[r*4+g][l]  = td_h_W row 2l+r, cols 8g..8g+7    (l<32)
  // pkC[r*8+g][l]  = hist_W row 2l+r, cols 8g..8g+7    (l<16)
  // pkZ[r*4+g][l]  = feat_W row 2l+r (diag 0), cols 8g..8g+7 (l<16)
  // pkDa[r*8+g][l] = wc_W  row 2l+r, cols 8g..8g+7     (l<16)
  __shared__ __align__(16) int4 pkB[8][32];
  __shared__ __align__(16) int4 pkC[16][16];
  __shared__ __align__(16) int4 pkZ[8][16];
  __shared__ __align__(16) int4 pkDa[16][16];
  // [e][ ccw 0..15 | mw 16..31 | hw 32..63 ] ; stride 84 (84%32=20) ->
  // rows 0..3 land on distinct banks for same-word reads.
  __shared__ __align__(16) int  inp_s[4][84];
  __shared__ float gp[4][256];    // [elem][gate row]
  __shared__ float msum_l[256];   // 1/msum[t]

  const int tid = threadIdx.x;
  const int b   = blockIdx.x;
  const int wv  = tid >> 6;          // 0..7
  const int ln  = tid & 63;
  const bool chain = (wv < 4);
  const int me  = wv & 3;
  const int b2  = (b << 2) | me;

  if (tid < 256) msum_l[tid] = 1.0f / msum[tid];
  // ---- stage pair-interleaved packed chain weights ----
  if (tid < 256){ const int l = tid & 31, g = (tid >> 5) & 3, r = tid >> 7;
    pkB[r*4+g][l] = mk4(td_h_W + (2*l+r)*32 + 8*g); }
  if (tid < 256){ const int l = tid & 15, g = (tid >> 4) & 7, r = tid >> 7;
    pkC[r*8+g][l] = mk4(hist_W + (2*l+r)*64 + 8*g); }
  if (tid < 128){ const int l = tid & 15, g = (tid >> 4) & 3, r = tid >> 6;
    const int row = 2*l + r, c0 = 8*g;
    float v[8];
    #pragma unroll
    for (int k = 0; k < 8; ++k){ const int c = c0+k; v[k] = (c==row) ? 0.f : feat_W[row*32+c]; }
    pkZ[r*4+g][l] = make_int4(pkf(v[0],v[1]),pkf(v[2],v[3]),pkf(v[4],v[5]),pkf(v[6],v[7])); }
  if (tid < 256){ const int l = tid & 15, g = (tid >> 4) & 7, r = tid >> 7;
    pkDa[r*8+g][l] = mk4(wc_W + (2*l+r)*64 + 8*g); }

  // ---- per-thread gate B-fragments (all 8 waves): 2 n-tiles x 4 k-steps ----
  int4 Wb[2][4];
  const int kg = ln >> 4;
  #pragma unroll
  for (int nt = 0; nt < 2; ++nt){
    const int col = (wv << 5) + (nt << 4) + (ln & 15);
    #pragma unroll
    for (int ks = 0; ks < 4; ++ks){
      const int k0 = (ks << 5) + (kg << 3);
      const float* src = (k0 < 64) ? (W_ih + (size_t)col*64 + k0)
                                   : (W_hh + (size_t)col*64 + (k0 - 64));
      Wb[nt][ks] = make_int4(pkf(src[0],src[1]), pkf(src[2],src[3]),
                             pkf(src[4],src[5]), pkf(src[6],src[7]));
    }
  }
  const int col0 = (wv << 5) + (ln & 15);
  const float bs0 = b_ih[col0]      + b_hh[col0];
  const float bs1 = b_ih[col0 + 16] + b_hh[col0 + 16];

  // ---- chain registers (pair-space) ----
  float2 thb = {0.f,0.f}, histb = {0.f,0.f}, featb = {0.f,0.f}, wcb = {0.f,0.f};
  float2 tdxb = {0.f,0.f}, ow = {0.f,0.f};
  float tdxd0 = 0.f, tdxd1 = 0.f;
  float x0=0.f,x1=0.f, m0=0.f,m1=0.f, d0=0.f,d1=0.f;   // step-t pairs (lanes<16)
  float h0=0.f,h1=0.f, c0=0.f,c1=0.f;                  // state pairs  (lanes<32)
  float loss_acc = 0.f;
  if (chain){
    if (ln < 32){
      thb = *(const float2*)(td_h_b + 2*ln);
      ow  = *(const float2*)(out_W + 2*ln);
    }
    if (ln < 16){
      histb = *(const float2*)(hist_b + 2*ln);
      featb = *(const float2*)(feat_b + 2*ln);
      wcb   = *(const float2*)(wc_b   + 2*ln);
      tdxb  = *(const float2*)(td_x_b + 2*ln);
      tdxd0 = td_x_W[(2*ln)*33]; tdxd1 = td_x_W[(2*ln+1)*33];
      const size_t base = (size_t)b2*8192 + 2*ln;
      const float2 xv = *(const float2*)(values + base);
      const float2 mv = *(const float2*)(masks  + base);
      const float2 dv = *(const float2*)(deltas + base);
      x0=xv.x; x1=xv.y; m0=mv.x; m1=mv.y; d0=dv.x; d1=dv.y;
    }
  }

  __syncthreads();

  for (int t = 0; t < 256; ++t){
    // ---- chain A-D (pair-space, shuffle-free) ----
    if (chain){
      const float xc0_=x0, xc1_=x1, mc0=m0, mc1=m1, dc0=d0, dc1=d1;
      int dw=0, mw=0, gxw=0;
      if (ln < 16){
        dw = pkf(dc0, dc1);
        mw = pkf(mc0, mc1);
        const float g0 = __expf(-fmaxf(fmaf(dc0, tdxd0, tdxb.x), 0.f));
        const float g1 = __expf(-fmaxf(fmaf(dc1, tdxd1, tdxb.y), 0.f));
        gxw = pkf(g0, g1);
        if (t < 255){   // prefetch t+1
          const size_t base = (size_t)b2*8192 + (size_t)(t+1)*32 + 2*ln;
          const float2 xv = *(const float2*)(values + base);
          const float2 mv = *(const float2*)(masks  + base);
          const float2 dv = *(const float2*)(deltas + base);
          x0=xv.x; x1=xv.y; m0=mv.x; m1=mv.y; d0=dv.x; d1=dv.y;
        }
      }
      // B: gamma_h rows 2l,2l+1 (lanes<32), K=32 packed; h pair *= exp
      int hw = 0;
      if (ln < 32){
        float a00=thb.x, a01=0.f, a10=thb.y, a11=0.f;
        #pragma unroll
        for (int g = 0; g < 4; ++g){
          const int4 w0 = pkB[g][ln];
          const int4 w1 = pkB[4+g][ln];
          a00 = dot2(w0.x, rl_i(dw,4*g+0), a00); a01 = dot2(w0.y, rl_i(dw,4*g+1), a01);
          a00 = dot2(w0.z, rl_i(dw,4*g+2), a00); a01 = dot2(w0.w, rl_i(dw,4*g+3), a01);
          a10 = dot2(w1.x, rl_i(dw,4*g+0), a10); a11 = dot2(w1.y, rl_i(dw,4*g+1), a11);
          a10 = dot2(w1.z, rl_i(dw,4*g+2), a10); a11 = dot2(w1.w, rl_i(dw,4*g+3), a11);
        }
        h0 *= __expf(-fmaxf(a00+a01, 0.f));
        h1 *= __expf(-fmaxf(a10+a11, 0.f));
        hw = pkf(h0, h1);                       // in-lane pack
        inp_s[me][32+ln] = hw;
      }
      // C: x_h rows 2l,2l+1 (lanes<16), K=64 (hw words in lanes 0..31)
      float ccw_v = 0.f;
      if (ln < 16){
        float b00=histb.x, b01=0.f, b10=histb.y, b11=0.f;
        #pragma unroll
        for (int g = 0; g < 8; ++g){
          const int4 w0 = pkC[g][ln];
          const int4 w1 = pkC[8+g][ln];
          b00 = dot2(w0.x, rl_i(hw,4*g+0), b00); b01 = dot2(w0.y, rl_i(hw,4*g+1), b01);
          b00 = dot2(w0.z, rl_i(hw,4*g+2), b00); b01 = dot2(w0.w, rl_i(hw,4*g+3), b01);
          b10 = dot2(w1.x, rl_i(hw,4*g+0), b10); b11 = dot2(w1.y, rl_i(hw,4*g+1), b11);
          b10 = dot2(w1.z, rl_i(hw,4*g+2), b10); b11 = dot2(w1.w, rl_i(hw,4*g+3), b11);
        }
        const float xh0 = b00+b01, xh1 = b10+b11;
        const float q0 = mc0*xc0_ + (1.f-mc0)*xh0;
        const float q1 = mc1*xc1_ + (1.f-mc1)*xh1;
        const int xcw = pkf(q0, q1);            // in-lane pack
        // D: z rows 2l,2l+1 (K=32) + alpha rows (K=64: gx|m)
        float z00=featb.x, z01=0.f, z10=featb.y, z11=0.f;
        #pragma unroll
        for (int g = 0; g < 4; ++g){
          const int4 w0 = pkZ[g][ln];
          const int4 w1 = pkZ[4+g][ln];
          z00 = dot2(w0.x, rl_i(xcw,4*g+0), z00); z01 = dot2(w0.y, rl_i(xcw,4*g+1), z01);
          z00 = dot2(w0.z, rl_i(xcw,4*g+2), z00); z01 = dot2(w0.w, rl_i(xcw,4*g+3), z01);
          z10 = dot2(w1.x, rl_i(xcw,4*g+0), z10); z11 = dot2(w1.y, rl_i(xcw,4*g+1), z11);
          z10 = dot2(w1.z, rl_i(xcw,4*g+2), z10); z11 = dot2(w1.w, rl_i(xcw,4*g+3), z11);
        }
        const float z0v = z00+z01, z1v = z10+z11;
        float a00=wcb.x, a01=0.f, a10=wcb.y, a11=0.f;
        #pragma unroll
        for (int g = 0; g < 8; ++g){
          const int4 w0 = pkDa[g][ln];
          const int4 w1 = pkDa[8+g][ln];
          const int k0 = 4*g;
          const int s0 = (k0   < 16) ? rl_i(gxw,k0  ) : rl_i(mw,k0-16);
          const int s1 = (k0+1 < 16) ? rl_i(gxw,k0+1) : rl_i(mw,k0-15);
          const int s2 = (k0+2 < 16) ? rl_i(gxw,k0+2) : rl_i(mw,k0-14);
          const int s3 = (k0+3 < 16) ? rl_i(gxw,k0+3) : rl_i(mw,k0-13);
          a00 = dot2(w0.x, s0, a00); a01 = dot2(w0.y, s1, a01);
          a00 = dot2(w0.z, s2, a00); a01 = dot2(w0.w, s3, a01);
          a10 = dot2(w1.x, s0, a10); a11 = dot2(w1.y, s1, a11);
          a10 = dot2(w1.z, s2, a10); a11 = dot2(w1.w, s3, a11);
        }
        const float al0 = a00+a01, al1 = a10+a11;
        const float ch0 = al0*z0v + (1.f-al0)*xh0;
        const float ch1 = al1*z1v + (1.f-al1)*xh1;
        loss_acc += ((fabsf(xc0_-xh0)+fabsf(xc0_-z0v)+fabsf(xc0_-ch0))*mc0
                   + (fabsf(xc1_-xh1)+fabsf(xc1_-z1v)+fabsf(xc1_-ch1))*mc1) * msum_l[t];
        const float cc0 = mc0*xc0_ + (1.f-mc0)*ch0;
        const float cc1 = mc1*xc1_ + (1.f-mc1)*ch1;
        *(float2*)(imps + (size_t)b2*8192 + (size_t)t*32 + 2*ln) = make_float2(cc0,cc1);
        ccw_v = 0.f; // silence unused warn path
        inp_s[me][ln]      = pkf(cc0, cc1);     // in-lane pack
        inp_s[me][16+ln]   = mw;
      }
      (void)ccw_v;
    }

    BAR();   // inp_s visible to all waves

    // ---- E: gate GEMM via MFMA; A rows = elems 0..3, rows 4..15 zero ----
    {
      const int arow = ln & 15;
      int4 A[4];
      if (arow < 4){
        #pragma unroll
        for (int ks = 0; ks < 4; ++ks)
          A[ks] = *reinterpret_cast<const int4*>(&inp_s[arow][(ks << 4) + (kg << 2)]);
      } else {
        #pragma unroll
        for (int ks = 0; ks < 4; ++ks) A[ks] = make_int4(0,0,0,0);
      }
      f32x4 acc0 = {bs0, bs0, bs0, bs0};
      f32x4 acc1 = {bs1, bs1, bs1, bs1};
      #pragma unroll
      for (int ks = 0; ks < 4; ++ks){
        acc0 = __builtin_amdgcn_mfma_f32_16x16x32_f16(
                 __builtin_bit_cast(h8, A[ks]), __builtin_bit_cast(h8, Wb[0][ks]), acc0, 0,0,0);
        acc1 = __builtin_amdgcn_mfma_f32_16x16x32_f16(
                 __builtin_bit_cast(h8, A[ks]), __builtin_bit_cast(h8, Wb[1][ks]), acc1, 0,0,0);
      }
      if (kg == 0){
        #pragma unroll
        for (int e = 0; e < 4; ++e){
          gp[e][col0]      = acc0[e];
          gp[e][col0 + 16] = acc1[e];
        }
      }
    }

    BAR();   // gates visible to chain waves

    // ---- F: LSTM pointwise update (chain waves, pair rows 2l,2l+1) ----
    if (chain && ln < 32){
      const float2 gi = *(const float2*)&gp[me][2*ln];
      const float2 gf = *(const float2*)&gp[me][64+2*ln];
      const float2 gg = *(const float2*)&gp[me][128+2*ln];
      const float2 go = *(const float2*)&gp[me][192+2*ln];
      c0 = fsig(gf.x)*c0 + fsig(gi.x)*ftanh(gg.x);
      c1 = fsig(gf.y)*c1 + fsig(gi.y)*ftanh(gg.y);
      h0 = fsig(go.x)*ftanh(c0);
      h1 = fsig(go.y)*ftanh(c1);
    }
  }

  // ---- epilogue: loss reduce + prediction/BCE (chain waves) ----
  if (chain){
    float l = (ln < 16) ? loss_acc : 0.f;
    l += __shfl_xor(l,32); l += __shfl_xor(l,16); l += __shfl_xor(l,8);
    l += __shfl_xor(l,4);  l += __shfl_xor(l,2);  l += __shfl_xor(l,1);
    if (ln == 0) atomicAdd(xl_acc, l);

    float p = (ln < 32) ? (h0*ow.x + h1*ow.y) : 0.f;
    p += __shfl_xor(p,32); p += __shfl_xor(p,16); p += __shfl_xor(p,8);
    p += __shfl_xor(p,4);  p += __shfl_xor(p,2);  p += __shfl_xor(p,1);
    if (ln == 0){
      const float y = p + out_b[0];
      predictions[b2] = fsig(y);
      const float lab = labels[b2];
      const float it  = is_train[b2];
      const float mx  = fmaxf(-y, 0.f);
      const float bce = y - y*lab + mx + __logf(__expf(-mx) + __expf(-y - mx));
      atomicAdd(bce_acc, bce * it);
    }
  }
}

// ---------------------------------------------------------------------------
// Kernel 3: finalize loss scalar
// ---------------------------------------------------------------------------
__global__ void final_kernel(const float* __restrict__ is_train,
                             const float* __restrict__ ws,
                             float* __restrict__ out){
  const int tid = threadIdx.x;
  __shared__ float red[256];
  red[tid] = is_train[tid] + is_train[tid+256] + is_train[tid+512] + is_train[tid+768];
  __syncthreads();
  for (int off = 128; off > 0; off >>= 1){
    if (tid < off) red[tid] += red[tid + off];
    __syncthreads();
  }
  if (tid == 0){
    const float yl = ws[1] / (red[0] + EPSF);
    out[0] = ws[0] / 256.0f + 0.1f * yl;
  }
}

extern "C" void kernel_launch(void* const* d_in, const int* in_sizes, int n_in,
                              void* d_out, int out_size, void* d_ws, size_t ws_size,
                              hipStream_t stream){
  const float* values   = (const float*)d_in[0];
  const float* masks    = (const float*)d_in[1];
  const float* deltas   = (const float*)d_in[2];
  const float* labels   = (const float*)d_in[5];
  const float* is_train = (const float*)d_in[6];
  const float* td_h_W   = (const float*)d_in[7];
  const float* td_h_b   = (const float*)d_in[8];
  const float* td_x_W   = (const float*)d_in[9];
  const float* td_x_b   = (const float*)d_in[10];
  const float* hist_W   = (const float*)d_in[11];
  const float* hist_b   = (const float*)d_in[12];
  const float* feat_W   = (const float*)d_in[13];
  const float* feat_b   = (const float*)d_in[14];
  const float* wc_W     = (const float*)d_in[15];
  const float* wc_b     = (const float*)d_in[16];
  const float* W_ih     = (const float*)d_in[17];
  const float* W_hh     = (const float*)d_in[18];
  const float* b_ih     = (const float*)d_in[19];
  const float* b_hh     = (const float*)d_in[20];
  const float* out_W    = (const float*)d_in[21];
  const float* out_b    = (const float*)d_in[22];

  float* out = (float*)d_out;                 // [0]=loss, [1..1025)=preds, [1025..)=imps
  float* ws  = (float*)d_ws;                  // [0]=xl_sum, [1]=bce_sum, [2..258)=msum

  hipMemsetAsync(ws, 0, 2*sizeof(float), stream);
  msum_kernel<<<256, 256, 0, stream>>>(masks, ws + 2);
  rits_kernel<<<256, 512, 0, stream>>>(values, masks, deltas, labels, is_train,
      td_h_W, td_h_b, td_x_W, td_x_b, hist_W, hist_b, feat_W, feat_b,
      wc_W, wc_b, W_ih, W_hh, b_ih, b_hh, out_W, out_b,
      ws + 2, ws + 0, ws + 1, out + 1, out + 1 + 1024);
  final_kernel<<<1, 256, 0, stream>>>(is_train, ws, out);
}

// Round 15
// 441.713 us; speedup vs baseline: 1.1690x; 1.1690x over previous
//
#include <hip/hip_runtime.h>

#define EPSF 1e-5f

typedef _Float16 h2f  __attribute__((ext_vector_type(2)));
typedef _Float16 h8   __attribute__((ext_vector_type(8)));
typedef float    f32x4 __attribute__((ext_vector_type(4)));

#if defined(__has_builtin)
#if __has_builtin(__builtin_amdgcn_fdot2)
#define HAVE_FDOT2 1
#endif
#endif

__device__ __forceinline__ float fsig(float x){ return 1.0f/(1.0f+__expf(-x)); }
__device__ __forceinline__ float ftanh(float x){
  float e = __expf(2.f*x);
  float r = (e-1.f)/(e+1.f);
  return (x > 15.f) ? 1.f : ((x < -15.f) ? -1.f : r);
}
__device__ __forceinline__ int pkf(float lo, float hi){
  return __builtin_bit_cast(int, __builtin_amdgcn_cvt_pkrtz(lo, hi));
}
__device__ __forceinline__ int4 mk4(const float* p){
  return make_int4(pkf(p[0],p[1]),pkf(p[2],p[3]),pkf(p[4],p[5]),pkf(p[6],p[7]));
}
__device__ __forceinline__ float dot2(int w, int x, float acc){
#ifdef HAVE_FDOT2
  return __builtin_amdgcn_fdot2(__builtin_bit_cast(h2f, w),
                                __builtin_bit_cast(h2f, x), acc, false);
#else
  h2f a = __builtin_bit_cast(h2f, w), b = __builtin_bit_cast(h2f, x);
  return acc + (float)a[0]*(float)b[0] + (float)a[1]*(float)b[1];
#endif
}
__device__ __forceinline__ int rl_i(int v, int l){ return __builtin_amdgcn_readlane(v, l); }
__device__ __forceinline__ float rl_f(float v, int l){
  return __int_as_float(__builtin_amdgcn_readlane(__float_as_int(v), l));
}
#define MFMA(A,B,C) __builtin_amdgcn_mfma_f32_16x16x32_f16( \
    __builtin_bit_cast(h8,(A)), __builtin_bit_cast(h8,(B)), (C), 0,0,0)
// light barrier: order LDS only; global loads/stores stay in flight
#define BAR() do{ asm volatile("s_waitcnt lgkmcnt(0)" ::: "memory"); __builtin_amdgcn_s_barrier(); }while(0)

// ---------------------------------------------------------------------------
// Kernel 1: msum[t] = sum_{b,n} masks[b,t,n] + EPS   (one block per t)
// ---------------------------------------------------------------------------
__global__ void msum_kernel(const float* __restrict__ masks, float* __restrict__ msum){
  const int t   = blockIdx.x;
  const int tid = threadIdx.x;
  const int b0  = tid >> 3;
  const int n4  = (tid & 7) << 2;
  float s = 0.f;
  #pragma unroll 4
  for (int i = 0; i < 32; ++i) {
    const int b = b0 + (i << 5);
    const float4 v = *reinterpret_cast<const float4*>(masks + ((size_t)b*256 + t)*32 + n4);
    s += v.x + v.y + v.z + v.w;
  }
  __shared__ float red[256];
  red[tid] = s; __syncthreads();
  for (int off = 128; off > 0; off >>= 1) {
    if (tid < off) red[tid] += red[tid + off];
    __syncthreads();
  }
  if (tid == 0) msum[t] = red[0] + EPSF;
}

// ---------------------------------------------------------------------------
// Kernel 2: persistent RNN. 256 blocks x 512 threads, 4 batch elems / block.
// r12 structure + ONE delta: gamma_h matvec moved OFF the chain into the E
// phase as an extra MFMA on waves 4-7 (gamma_h depends only on d, which is
// prefetched; chain packs dw(t+1) words off-path at end of its phase).
// Chain's B phase (dw pack + 16 dot2, all serial before hw) collapses to
// one conflict-free LDS read + exp. Chain also drops fB/thb (-17 live regs).
// ---------------------------------------------------------------------------
__global__ __launch_bounds__(512)
__attribute__((amdgpu_waves_per_eu(2, 2)))
void rits_kernel(
  const float* __restrict__ values, const float* __restrict__ masks,
  const float* __restrict__ deltas, const float* __restrict__ labels,
  const float* __restrict__ is_train,
  const float* __restrict__ td_h_W, const float* __restrict__ td_h_b,
  const float* __restrict__ td_x_W, const float* __restrict__ td_x_b,
  const float* __restrict__ hist_W, const float* __restrict__ hist_b,
  const float* __restrict__ feat_W, const float* __restrict__ feat_b,
  const float* __restrict__ wc_W,  const float* __restrict__ wc_b,
  const float* __restrict__ W_ih,  const float* __restrict__ W_hh,
  const float* __restrict__ b_ih,  const float* __restrict__ b_hh,
  const float* __restrict__ out_W, const float* __restrict__ out_b,
  const float* __restrict__ msum,
  float* __restrict__ xl_acc, float* __restrict__ bce_acc,
  float* __restrict__ predictions, float* __restrict__ imps)
{
  // [e][ ccw 0..15 | mw 16..31 | hw 32..63 ] ; stride 84 (84%32=20) ->
  // rows 0..3 land on distinct banks for same-word reads.
  __shared__ __align__(16) int  inp_s[4][84];
  __shared__ __align__(16) int  dw_s[4][20];   // dw(t+1) words; stride 20 -> rows on distinct quads
  __shared__ float sB[4][64];     // gamma_h linear (pre-exp) for the step being entered
  __shared__ float gp[4][256];    // [elem][gate row]
  __shared__ float msum_l[256];   // 1/msum[t]

  const int tid = threadIdx.x;
  const int b   = blockIdx.x;
  const int wv  = tid >> 6;          // 0..7
  const int ln  = tid & 63;
  const bool chain = (wv < 4);
  const int me  = wv & 3;
  const int b2  = (b << 2) | me;
  const int kg  = ln >> 4;
  const int arow = ln & 15;

  if (tid < 256) msum_l[tid] = 1.0f / msum[tid];

  // ---- per-thread gate B-fragments (all 8 waves): 2 n-tiles x 4 k-steps ----
  int4 Wb[2][4];
  #pragma unroll
  for (int nt = 0; nt < 2; ++nt){
    const int col = (wv << 5) + (nt << 4) + (ln & 15);
    #pragma unroll
    for (int ks = 0; ks < 4; ++ks){
      const int k0 = (ks << 5) + (kg << 3);
      const float* src = (k0 < 64) ? (W_ih + (size_t)col*64 + k0)
                                   : (W_hh + (size_t)col*64 + (k0 - 64));
      Wb[nt][ks] = make_int4(pkf(src[0],src[1]), pkf(src[2],src[3]),
                             pkf(src[4],src[5]), pkf(src[6],src[7]));
    }
  }
  const int col0 = (wv << 5) + (ln & 15);
  const float bs0 = b_ih[col0]      + b_hh[col0];
  const float bs1 = b_ih[col0 + 16] + b_hh[col0 + 16];

  // ---- gamma_h B-fragment on waves 4-7 (tile wv-4 -> cols (wv-4)*16+c16) ----
  int4 fGh = make_int4(0,0,0,0);
  float ghb = 0.f; int colj = 0;
  if (wv >= 4){
    colj = ((wv - 4) << 4) | (ln & 15);
    fGh  = mk4(td_h_W + colj*32 + kg*8);
    ghb  = td_h_b[colj];
  }

  // ---- chain-wave VGPR weights + registers (no fB/thb -- gamma_h is in E) ----
  int4  fC[8];      // hist_W row (ln&31) (K=64)
  int4  fDa[8];     // wc_W row (ln&31) (K=64, [gx|m])
  float wz[32];     // feat_W row (ln&31), fp32, diag 0
  float tdxd_r=0.f, tdxb_r=0.f, histb_r=0.f, featb_r=0.f, wcb_r=0.f;
  float xv=0.f, mv=0.f, dv=0.f;
  if (chain){
    const int nr = ln & 31;
    #pragma unroll
    for (int g = 0; g < 8; ++g) fC[g] = mk4(hist_W + nr*64 + 8*g);
    #pragma unroll
    for (int g = 0; g < 8; ++g) fDa[g] = mk4(wc_W + nr*64 + 8*g);
    #pragma unroll
    for (int k = 0; k < 32; ++k) wz[k] = (k==nr) ? 0.f : feat_W[nr*32 + k];
    if (ln < 32){
      tdxd_r  = td_x_W[ln*33];
      tdxb_r  = td_x_b[ln];
      histb_r = hist_b[ln];
      featb_r = feat_b[ln];
      wcb_r   = wc_b[ln];
      const size_t base = (size_t)b2*8192 + ln;
      xv = values[base]; mv = masks[base]; dv = deltas[base];
    }
  }
  float h_reg = 0.f, c_reg = 0.f, loss_acc = 0.f;
  const int i0 = (2*ln) & 63, i1 = (2*ln+1) & 63;
  const int j0 = (2*ln-32) & 63, j1 = (2*ln-31) & 63;

  __syncthreads();

  // ---- prologue: dw(0) -> dw_s ; gamma_h_lin(0) -> sB ----
  if (chain){
    const int dwn = pkf(__shfl(dv, i0), __shfl(dv, i1));
    if (ln < 16) dw_s[me][ln] = dwn;
  }
  __syncthreads();
  if (wv >= 4){
    int4 A = make_int4(0,0,0,0);
    if (arow < 4) A = *reinterpret_cast<const int4*>(&dw_s[arow][kg << 2]);
    f32x4 acc = {ghb, ghb, ghb, ghb};
    acc = MFMA(A, fGh, acc);
    if (kg == 0){
      #pragma unroll
      for (int e = 0; e < 4; ++e) sB[e][colj] = acc[e];
    }
  }
  __syncthreads();

  for (int t = 0; t < 256; ++t){
    // ---- chain A-D ----
    if (chain){
      const float x_cur = xv, m_cur = mv, d_cur = dv;
      // decay h from precomputed gamma_h linear (one LDS read + exp)
      const float sb = sB[me][ln];
      float gx_r = 0.f;
      if (ln < 32){
        gx_r = __expf(-fmaxf(fmaf(d_cur, tdxd_r, tdxb_r), 0.f));
        if (t < 255){
          const size_t base = (size_t)b2*8192 + (size_t)(t+1)*32 + ln;
          xv = values[base]; mv = masks[base]; dv = deltas[base];
        }
      }
      // aw pack (inputs ready; off the serial path)
      const float ga  = __shfl(gx_r,  i0), gb_ = __shfl(gx_r,  i1);
      const float ma_ = __shfl(m_cur, j0), mb_ = __shfl(m_cur, j1);
      const int aw = (ln < 16) ? pkf(ga, gb_) : pkf(ma_, mb_);     // gx|m pairs

      h_reg *= __expf(-fmaxf(sb, 0.f));
      const int hw = pkf(__shfl(h_reg, i0), __shfl(h_reg, i1));    // h pairs
      // C: x_h (32 rows, K=64, VGPR weights); x_c
      float xh_v = 0.f, x_c_v = 0.f;
      if (ln < 32){
        float a0 = histb_r, a1 = 0.f, a2 = 0.f, a3 = 0.f;
        #pragma unroll
        for (int g4 = 0; g4 < 8; ++g4){
          const int4 w = fC[g4];
          a0 = dot2(w.x, rl_i(hw, 4*g4+0), a0);
          a1 = dot2(w.y, rl_i(hw, 4*g4+1), a1);
          a2 = dot2(w.z, rl_i(hw, 4*g4+2), a2);
          a3 = dot2(w.w, rl_i(hw, 4*g4+3), a3);
        }
        xh_v  = (a0+a1)+(a2+a3);
        x_c_v = m_cur*x_cur + (1.f-m_cur)*xh_v;
      }
      // D: z (fp32 readlane of x_c -- no pack), alpha, c_h, loss, imputation
      float ccv = 0.f;
      if (ln < 32){
        float z0 = featb_r, z1 = 0.f, z2 = 0.f, z3 = 0.f;
        #pragma unroll
        for (int k = 0; k < 32; k += 4){
          z0 = fmaf(rl_f(x_c_v, k+0), wz[k+0], z0);
          z1 = fmaf(rl_f(x_c_v, k+1), wz[k+1], z1);
          z2 = fmaf(rl_f(x_c_v, k+2), wz[k+2], z2);
          z3 = fmaf(rl_f(x_c_v, k+3), wz[k+3], z3);
        }
        const float z = (z0+z1)+(z2+z3);
        float a0 = wcb_r, a1 = 0.f, a2 = 0.f, a3 = 0.f;
        #pragma unroll
        for (int g4 = 0; g4 < 8; ++g4){
          const int4 w = fDa[g4];
          a0 = dot2(w.x, rl_i(aw, 4*g4+0), a0);
          a1 = dot2(w.y, rl_i(aw, 4*g4+1), a1);
          a2 = dot2(w.z, rl_i(aw, 4*g4+2), a2);
          a3 = dot2(w.w, rl_i(aw, 4*g4+3), a3);
        }
        const float al = (a0+a1)+(a2+a3);
        const float ch = al*z + (1.f-al)*xh_v;
        loss_acc += (fabsf(x_cur-xh_v)+fabsf(x_cur-z)+fabsf(x_cur-ch))*m_cur*msum_l[t];
        ccv = m_cur*x_cur + (1.f-m_cur)*ch;
        imps[(size_t)b2*8192 + (size_t)t*32 + ln] = ccv;
      }
      const int ccw = pkf(__shfl(ccv, i0), __shfl(ccv, i1));      // words 0..15
      inp_s[me][ln] = (ln < 16) ? ccw : (ln < 32 ? aw : hw);
      // dw(t+1) pack for E's gamma_h MFMA (off critical path; dv = d(t+1))
      if (t < 255){
        const int dwn = pkf(__shfl(dv, i0), __shfl(dv, i1));
        if (ln < 16) dw_s[me][ln] = dwn;
      }
    }

    BAR();   // inp_s, dw_s visible to all waves

    // ---- E: gate GEMM via MFMA; A rows = elems 0..3, rows 4..15 zero ----
    {
      int4 A[4];
      if (arow < 4){
        #pragma unroll
        for (int ks = 0; ks < 4; ++ks)
          A[ks] = *reinterpret_cast<const int4*>(&inp_s[arow][(ks << 4) + (kg << 2)]);
      } else {
        #pragma unroll
        for (int ks = 0; ks < 4; ++ks) A[ks] = make_int4(0,0,0,0);
      }
      f32x4 acc0 = {bs0, bs0, bs0, bs0};
      f32x4 acc1 = {bs1, bs1, bs1, bs1};
      #pragma unroll
      for (int ks = 0; ks < 4; ++ks){
        acc0 = __builtin_amdgcn_mfma_f32_16x16x32_f16(
                 __builtin_bit_cast(h8, A[ks]), __builtin_bit_cast(h8, Wb[0][ks]), acc0, 0,0,0);
        acc1 = __builtin_amdgcn_mfma_f32_16x16x32_f16(
                 __builtin_bit_cast(h8, A[ks]), __builtin_bit_cast(h8, Wb[1][ks]), acc1, 0,0,0);
      }
      // C/D: col=lane&15, row=(lane>>4)*4+reg -> kg==0 lanes hold rows 0-3
      if (kg == 0){
        #pragma unroll
        for (int e = 0; e < 4; ++e){
          gp[e][col0]      = acc0[e];
          gp[e][col0 + 16] = acc1[e];
        }
      }
    }
    // ---- E extra (waves 4-7): gamma_h_lin(t+1) MFMA -> sB ----
    if (wv >= 4){
      int4 Agh = make_int4(0,0,0,0);
      if (arow < 4) Agh = *reinterpret_cast<const int4*>(&dw_s[arow][kg << 2]);
      f32x4 accg = {ghb, ghb, ghb, ghb};
      accg = MFMA(Agh, fGh, accg);
      if (kg == 0){
        #pragma unroll
        for (int e = 0; e < 4; ++e) sB[e][colj] = accg[e];
      }
    }

    BAR();   // gates + sB visible to chain waves

    // ---- F: LSTM pointwise update (chain waves) ----
    if (chain){
      const float ig = gp[me][ln];
      const float fg = gp[me][64+ln];
      const float gg = gp[me][128+ln];
      const float og = gp[me][192+ln];
      c_reg = fsig(fg)*c_reg + fsig(ig)*ftanh(gg);
      h_reg = fsig(og)*ftanh(c_reg);
    }
  }

  // ---- epilogue: loss reduce + prediction/BCE (chain waves) ----
  if (chain){
    float l = loss_acc;   // nonzero only on ln<32
    l += __shfl_xor(l,16); l += __shfl_xor(l,8);
    l += __shfl_xor(l,4);  l += __shfl_xor(l,2); l += __shfl_xor(l,1);
    if (ln == 0) atomicAdd(xl_acc, l);

    float p = h_reg * out_W[ln];
    p += __shfl_xor(p,32); p += __shfl_xor(p,16); p += __shfl_xor(p,8);
    p += __shfl_xor(p,4);  p += __shfl_xor(p,2);  p += __shfl_xor(p,1);
    if (ln == 0){
      const float y = p + out_b[0];
      predictions[b2] = fsig(y);
      const float lab = labels[b2];
      const float it  = is_train[b2];
      const float mx  = fmaxf(-y, 0.f);
      const float bce = y - y*lab + mx + __logf(__expf(-mx) + __expf(-y - mx));
      atomicAdd(bce_acc, bce * it);
    }
  }
}

// ---------------------------------------------------------------------------
// Kernel 3: finalize loss scalar
// ---------------------------------------------------------------------------
__global__ void final_kernel(const float* __restrict__ is_train,
                             const float* __restrict__ ws,
                             float* __restrict__ out){
  const int tid = threadIdx.x;
  __shared__ float red[256];
  red[tid] = is_train[tid] + is_train[tid+256] + is_train[tid+512] + is_train[tid+768];
  __syncthreads();
  for (int off = 128; off > 0; off >>= 1){
    if (tid < off) red[tid] += red[tid + off];
    __syncthreads();
  }
  if (tid == 0){
    const float yl = ws[1] / (red[0] + EPSF);
    out[0] = ws[0] / 256.0f + 0.1f * yl;
  }
}

extern "C" void kernel_launch(void* const* d_in, const int* in_sizes, int n_in,
                              void* d_out, int out_size, void* d_ws, size_t ws_size,
                              hipStream_t stream){
  const float* values   = (const float*)d_in[0];
  const float* masks    = (const float*)d_in[1];
  const float* deltas   = (const float*)d_in[2];
  const float* labels   = (const float*)d_in[5];
  const float* is_train = (const float*)d_in[6];
  const float* td_h_W   = (const float*)d_in[7];
  const float* td_h_b   = (const float*)d_in[8];
  const float* td_x_W   = (const float*)d_in[9];
  const float* td_x_b   = (const float*)d_in[10];
  const float* hist_W   = (const float*)d_in[11];
  const float* hist_b   = (const float*)d_in[12];
  const float* feat_W   = (const float*)d_in[13];
  const float* feat_b   = (const float*)d_in[14];
  const float* wc_W     = (const float*)d_in[15];
  const float* wc_b     = (const float*)d_in[16];
  const float* W_ih     = (const float*)d_in[17];
  const float* W_hh     = (const float*)d_in[18];
  const float* b_ih     = (const float*)d_in[19];
  const float* b_hh     = (const float*)d_in[20];
  const float* out_W    = (const float*)d_in[21];
  const float* out_b    = (const float*)d_in[22];

  float* out = (float*)d_out;                 // [0]=loss, [1..1025)=preds, [1025..)=imps
  float* ws  = (float*)d_ws;                  // [0]=xl_sum, [1]=bce_sum, [2..258)=msum

  hipMemsetAsync(ws, 0, 2*sizeof(float), stream);
  msum_kernel<<<256, 256, 0, stream>>>(masks, ws + 2);
  rits_kernel<<<256, 512, 0, stream>>>(values, masks, deltas, labels, is_train,
      td_h_W, td_h_b, td_x_W, td_x_b, hist_W, hist_b, feat_W, feat_b,
      wc_W, wc_b, W_ih, W_hh, b_ih, b_hh, out_W, out_b,
      ws + 2, ws + 0, ws + 1, out + 1, out + 1 + 1024);
  final_kernel<<<1, 256, 0, stream>>>(is_train, ws, out);
}

// Round 16
// 434.747 us; speedup vs baseline: 1.1877x; 1.0160x over previous
//
#include <hip/hip_runtime.h>

#define EPSF 1e-5f

typedef _Float16 h2f  __attribute__((ext_vector_type(2)));
typedef _Float16 h8   __attribute__((ext_vector_type(8)));
typedef float    f32x4 __attribute__((ext_vector_type(4)));

#if defined(__has_builtin)
#if __has_builtin(__builtin_amdgcn_fdot2)
#define HAVE_FDOT2 1
#endif
#endif

__device__ __forceinline__ float fsig(float x){ return 1.0f/(1.0f+__expf(-x)); }
__device__ __forceinline__ float ftanh(float x){
  float e = __expf(2.f*x);
  float r = (e-1.f)/(e+1.f);
  return (x > 15.f) ? 1.f : ((x < -15.f) ? -1.f : r);
}
__device__ __forceinline__ int pkf(float lo, float hi){
  return __builtin_bit_cast(int, __builtin_amdgcn_cvt_pkrtz(lo, hi));
}
__device__ __forceinline__ int4 mk4(const float* p){
  return make_int4(pkf(p[0],p[1]),pkf(p[2],p[3]),pkf(p[4],p[5]),pkf(p[6],p[7]));
}
__device__ __forceinline__ float dot2(int w, int x, float acc){
#ifdef HAVE_FDOT2
  return __builtin_amdgcn_fdot2(__builtin_bit_cast(h2f, w),
                                __builtin_bit_cast(h2f, x), acc, false);
#else
  h2f a = __builtin_bit_cast(h2f, w), b = __builtin_bit_cast(h2f, x);
  return acc + (float)a[0]*(float)b[0] + (float)a[1]*(float)b[1];
#endif
}
__device__ __forceinline__ int rl_i(int v, int l){ return __builtin_amdgcn_readlane(v, l); }
__device__ __forceinline__ float rl_f(float v, int l){
  return __int_as_float(__builtin_amdgcn_readlane(__float_as_int(v), l));
}
#define MFMA(A,B,C) __builtin_amdgcn_mfma_f32_16x16x32_f16( \
    __builtin_bit_cast(h8,(A)), __builtin_bit_cast(h8,(B)), (C), 0,0,0)
// light barrier: order LDS only; global loads/stores stay in flight
#define BAR() do{ asm volatile("s_waitcnt lgkmcnt(0)" ::: "memory"); __builtin_amdgcn_s_barrier(); }while(0)

// ---------------------------------------------------------------------------
// Kernel 1: msum[t] = sum_{b,n} masks[b,t,n] + EPS   (one block per t)
// ---------------------------------------------------------------------------
__global__ void msum_kernel(const float* __restrict__ masks, float* __restrict__ msum){
  const int t   = blockIdx.x;
  const int tid = threadIdx.x;
  const int b0  = tid >> 3;
  const int n4  = (tid & 7) << 2;
  float s = 0.f;
  #pragma unroll 4
  for (int i = 0; i < 32; ++i) {
    const int b = b0 + (i << 5);
    const float4 v = *reinterpret_cast<const float4*>(masks + ((size_t)b*256 + t)*32 + n4);
    s += v.x + v.y + v.z + v.w;
  }
  __shared__ float red[256];
  red[tid] = s; __syncthreads();
  for (int off = 128; off > 0; off >>= 1) {
    if (tid < off) red[tid] += red[tid + off];
    __syncthreads();
  }
  if (tid == 0) msum[t] = red[0] + EPSF;
}

// ---------------------------------------------------------------------------
// Kernel 2: persistent RNN. 256 blocks x 512 threads, 4 batch elems / block.
// r15 + ONE delta: the alpha matvec ALSO moves off the chain into E (waves
// 4-5, 2 MFMA over [gx|m](t+1) words packed off-path by the chain). gamma_x
// now leaves the chain's critical path entirely (it feeds only alpha).
// Chain drops fDa (-32 live regs). Chain critical path per step is now:
// F -> decay(sB) -> hw pack -> C matvec -> x_c -> z matvec -> ch(sAl) -> cc.
// ---------------------------------------------------------------------------
__global__ __launch_bounds__(512)
__attribute__((amdgpu_waves_per_eu(2, 2)))
void rits_kernel(
  const float* __restrict__ values, const float* __restrict__ masks,
  const float* __restrict__ deltas, const float* __restrict__ labels,
  const float* __restrict__ is_train,
  const float* __restrict__ td_h_W, const float* __restrict__ td_h_b,
  const float* __restrict__ td_x_W, const float* __restrict__ td_x_b,
  const float* __restrict__ hist_W, const float* __restrict__ hist_b,
  const float* __restrict__ feat_W, const float* __restrict__ feat_b,
  const float* __restrict__ wc_W,  const float* __restrict__ wc_b,
  const float* __restrict__ W_ih,  const float* __restrict__ W_hh,
  const float* __restrict__ b_ih,  const float* __restrict__ b_hh,
  const float* __restrict__ out_W, const float* __restrict__ out_b,
  const float* __restrict__ msum,
  float* __restrict__ xl_acc, float* __restrict__ bce_acc,
  float* __restrict__ predictions, float* __restrict__ imps)
{
  // [e][ ccw 0..15 | mw 16..31 | hw 32..63 ] ; stride 84 (84%32=20) ->
  // rows 0..3 land on distinct banks for same-word reads.
  __shared__ __align__(16) int  inp_s[4][84];
  // future words for E: [e][ dw 0..15 | gxw 16..31 | mw 32..47 ]; stride 52
  __shared__ __align__(16) int  nb[4][52];
  __shared__ float sB[4][64];     // gamma_h linear (pre-exp) for the step entered
  __shared__ float sAl[4][32];    // alpha for the step entered
  __shared__ float gp[4][256];    // [elem][gate row]
  __shared__ float msum_l[256];   // 1/msum[t]

  const int tid = threadIdx.x;
  const int b   = blockIdx.x;
  const int wv  = tid >> 6;          // 0..7
  const int ln  = tid & 63;
  const bool chain = (wv < 4);
  const int me  = wv & 3;
  const int b2  = (b << 2) | me;
  const int kg  = ln >> 4;
  const int arow = ln & 15;

  if (tid < 256) msum_l[tid] = 1.0f / msum[tid];

  // ---- per-thread gate B-fragments (all 8 waves): 2 n-tiles x 4 k-steps ----
  int4 Wb[2][4];
  #pragma unroll
  for (int nt = 0; nt < 2; ++nt){
    const int col = (wv << 5) + (nt << 4) + (ln & 15);
    #pragma unroll
    for (int ks = 0; ks < 4; ++ks){
      const int k0 = (ks << 5) + (kg << 3);
      const float* src = (k0 < 64) ? (W_ih + (size_t)col*64 + k0)
                                   : (W_hh + (size_t)col*64 + (k0 - 64));
      Wb[nt][ks] = make_int4(pkf(src[0],src[1]), pkf(src[2],src[3]),
                             pkf(src[4],src[5]), pkf(src[6],src[7]));
    }
  }
  const int col0 = (wv << 5) + (ln & 15);
  const float bs0 = b_ih[col0]      + b_hh[col0];
  const float bs1 = b_ih[col0 + 16] + b_hh[col0 + 16];

  // ---- E-wave extra fragments: gamma_h (waves 4-7) + alpha (waves 4-5) ----
  int4 fGh = make_int4(0,0,0,0);
  float ghb = 0.f; int colj = 0;
  int4 fA0 = make_int4(0,0,0,0), fA1 = make_int4(0,0,0,0);
  float alb = 0.f; int colA = 0;
  if (wv >= 4){
    colj = ((wv - 4) << 4) | (ln & 15);
    fGh  = mk4(td_h_W + colj*32 + kg*8);
    ghb  = td_h_b[colj];
    if (wv < 6){
      colA = ((wv - 4) << 4) | (ln & 15);
      fA0  = mk4(wc_W + colA*64 + kg*8);
      fA1  = mk4(wc_W + colA*64 + 32 + kg*8);
      alb  = wc_b[colA];
    }
  }

  // ---- chain-wave VGPR weights + registers ----
  int4  fC[8];      // hist_W row (ln&31) (K=64)
  float wz[32];     // feat_W row (ln&31), fp32, diag 0
  float tdxd_r=0.f, tdxb_r=0.f, histb_r=0.f, featb_r=0.f;
  float xv=0.f, mv=0.f, dv=0.f;
  if (chain){
    const int nr = ln & 31;
    #pragma unroll
    for (int g = 0; g < 8; ++g) fC[g] = mk4(hist_W + nr*64 + 8*g);
    #pragma unroll
    for (int k = 0; k < 32; ++k) wz[k] = (k==nr) ? 0.f : feat_W[nr*32 + k];
    if (ln < 32){
      tdxd_r  = td_x_W[ln*33];
      tdxb_r  = td_x_b[ln];
      histb_r = hist_b[ln];
      featb_r = feat_b[ln];
      const size_t base = (size_t)b2*8192 + ln;
      xv = values[base]; mv = masks[base]; dv = deltas[base];
    }
  }
  float h_reg = 0.f, c_reg = 0.f, loss_acc = 0.f;
  const int i0 = (2*ln) & 63, i1 = (2*ln+1) & 63;
  const int j0 = (2*ln-32) & 63, j1 = (2*ln-31) & 63;

  __syncthreads();

  // ---- prologue: nb(0) = dw/gxw/mw(0) ; E computes sB(0), sAl(0) ----
  if (chain){
    float gx0 = 0.f;
    if (ln < 32) gx0 = __expf(-fmaxf(fmaf(dv, tdxd_r, tdxb_r), 0.f));
    const int dw0 = pkf(__shfl(dv,  i0), __shfl(dv,  i1));
    const int gw0 = pkf(__shfl(gx0, i0), __shfl(gx0, i1));
    const int mw0 = pkf(__shfl(mv,  i0), __shfl(mv,  i1));
    if (ln < 16){ nb[me][ln]=dw0; nb[me][16+ln]=gw0; nb[me][32+ln]=mw0; }
  }
  __syncthreads();
  if (wv >= 4){
    int4 A = make_int4(0,0,0,0);
    if (arow < 4) A = *reinterpret_cast<const int4*>(&nb[arow][kg << 2]);
    f32x4 acc = {ghb, ghb, ghb, ghb};
    acc = MFMA(A, fGh, acc);
    if (kg == 0){
      #pragma unroll
      for (int e = 0; e < 4; ++e) sB[e][colj] = acc[e];
    }
    if (wv < 6){
      int4 A0 = make_int4(0,0,0,0), A1 = make_int4(0,0,0,0);
      if (arow < 4){
        A0 = *reinterpret_cast<const int4*>(&nb[arow][16 + (kg << 2)]);
        A1 = *reinterpret_cast<const int4*>(&nb[arow][32 + (kg << 2)]);
      }
      f32x4 aacc = {alb, alb, alb, alb};
      aacc = MFMA(A0, fA0, aacc);
      aacc = MFMA(A1, fA1, aacc);
      if (kg == 0){
        #pragma unroll
        for (int e = 0; e < 4; ++e) sAl[e][colA] = aacc[e];
      }
    }
  }
  __syncthreads();

  for (int t = 0; t < 256; ++t){
    // ---- chain: decay + C + z + combine (alpha/gamma_h precomputed) ----
    if (chain){
      const float x_cur = xv, m_cur = mv;
      const float sb = sB[me][ln];
      const float al = (ln < 32) ? sAl[me][ln] : 0.f;
      if (ln < 32 && t < 255){
        const size_t base = (size_t)b2*8192 + (size_t)(t+1)*32 + ln;
        xv = values[base]; mv = masks[base]; dv = deltas[base];
      }
      // mw(t) pack for gate GEMM (lanes 16-31; off the serial path)
      const float ma_ = __shfl(m_cur, j0), mb_ = __shfl(m_cur, j1);
      const int mwc = pkf(ma_, mb_);

      h_reg *= __expf(-fmaxf(sb, 0.f));
      const int hw = pkf(__shfl(h_reg, i0), __shfl(h_reg, i1));    // h pairs
      // C: x_h (32 rows, K=64, VGPR weights); x_c
      float xh_v = 0.f, x_c_v = 0.f;
      if (ln < 32){
        float a0 = histb_r, a1 = 0.f, a2 = 0.f, a3 = 0.f;
        #pragma unroll
        for (int g4 = 0; g4 < 8; ++g4){
          const int4 w = fC[g4];
          a0 = dot2(w.x, rl_i(hw, 4*g4+0), a0);
          a1 = dot2(w.y, rl_i(hw, 4*g4+1), a1);
          a2 = dot2(w.z, rl_i(hw, 4*g4+2), a2);
          a3 = dot2(w.w, rl_i(hw, 4*g4+3), a3);
        }
        xh_v  = (a0+a1)+(a2+a3);
        x_c_v = m_cur*x_cur + (1.f-m_cur)*xh_v;
      }
      // D: z (fp32 readlane of x_c), combine with precomputed alpha
      float ccv = 0.f;
      if (ln < 32){
        float z0 = featb_r, z1 = 0.f, z2 = 0.f, z3 = 0.f;
        #pragma unroll
        for (int k = 0; k < 32; k += 4){
          z0 = fmaf(rl_f(x_c_v, k+0), wz[k+0], z0);
          z1 = fmaf(rl_f(x_c_v, k+1), wz[k+1], z1);
          z2 = fmaf(rl_f(x_c_v, k+2), wz[k+2], z2);
          z3 = fmaf(rl_f(x_c_v, k+3), wz[k+3], z3);
        }
        const float z = (z0+z1)+(z2+z3);
        const float ch = al*z + (1.f-al)*xh_v;
        loss_acc += (fabsf(x_cur-xh_v)+fabsf(x_cur-z)+fabsf(x_cur-ch))*m_cur*msum_l[t];
        ccv = m_cur*x_cur + (1.f-m_cur)*ch;
        imps[(size_t)b2*8192 + (size_t)t*32 + ln] = ccv;
      }
      const int ccw = pkf(__shfl(ccv, i0), __shfl(ccv, i1));      // words 0..15
      inp_s[me][ln] = (ln < 16) ? ccw : (ln < 32 ? mwc : hw);
      // future words for E (off critical path; dv/mv hold t+1)
      {
        float gxn = 0.f;
        if (ln < 32) gxn = __expf(-fmaxf(fmaf(dv, tdxd_r, tdxb_r), 0.f));
        const int dwn = pkf(__shfl(dv,  i0), __shfl(dv,  i1));
        const int gwn = pkf(__shfl(gxn, i0), __shfl(gxn, i1));
        const int mwn = pkf(__shfl(mv,  i0), __shfl(mv,  i1));
        if (ln < 16){ nb[me][ln]=dwn; nb[me][16+ln]=gwn; nb[me][32+ln]=mwn; }
      }
    }

    BAR();   // inp_s, nb visible to all waves

    // ---- E: gate GEMM via MFMA; A rows = elems 0..3, rows 4..15 zero ----
    {
      int4 A[4];
      if (arow < 4){
        #pragma unroll
        for (int ks = 0; ks < 4; ++ks)
          A[ks] = *reinterpret_cast<const int4*>(&inp_s[arow][(ks << 4) + (kg << 2)]);
      } else {
        #pragma unroll
        for (int ks = 0; ks < 4; ++ks) A[ks] = make_int4(0,0,0,0);
      }
      f32x4 acc0 = {bs0, bs0, bs0, bs0};
      f32x4 acc1 = {bs1, bs1, bs1, bs1};
      #pragma unroll
      for (int ks = 0; ks < 4; ++ks){
        acc0 = __builtin_amdgcn_mfma_f32_16x16x32_f16(
                 __builtin_bit_cast(h8, A[ks]), __builtin_bit_cast(h8, Wb[0][ks]), acc0, 0,0,0);
        acc1 = __builtin_amdgcn_mfma_f32_16x16x32_f16(
                 __builtin_bit_cast(h8, A[ks]), __builtin_bit_cast(h8, Wb[1][ks]), acc1, 0,0,0);
      }
      // C/D: col=lane&15, row=(lane>>4)*4+reg -> kg==0 lanes hold rows 0-3
      if (kg == 0){
        #pragma unroll
        for (int e = 0; e < 4; ++e){
          gp[e][col0]      = acc0[e];
          gp[e][col0 + 16] = acc1[e];
        }
      }
    }
    // ---- E extra (waves 4-7): gamma_h(t+1); (waves 4-5): alpha(t+1) ----
    if (wv >= 4){
      int4 Agh = make_int4(0,0,0,0);
      if (arow < 4) Agh = *reinterpret_cast<const int4*>(&nb[arow][kg << 2]);
      f32x4 accg = {ghb, ghb, ghb, ghb};
      accg = MFMA(Agh, fGh, accg);
      if (kg == 0){
        #pragma unroll
        for (int e = 0; e < 4; ++e) sB[e][colj] = accg[e];
      }
      if (wv < 6){
        int4 A0 = make_int4(0,0,0,0), A1 = make_int4(0,0,0,0);
        if (arow < 4){
          A0 = *reinterpret_cast<const int4*>(&nb[arow][16 + (kg << 2)]);
          A1 = *reinterpret_cast<const int4*>(&nb[arow][32 + (kg << 2)]);
        }
        f32x4 aacc = {alb, alb, alb, alb};
        aacc = MFMA(A0, fA0, aacc);
        aacc = MFMA(A1, fA1, aacc);
        if (kg == 0){
          #pragma unroll
          for (int e = 0; e < 4; ++e) sAl[e][colA] = aacc[e];
        }
      }
    }

    BAR();   // gates + sB + sAl visible to chain waves

    // ---- F: LSTM pointwise update (chain waves) ----
    if (chain){
      const float ig = gp[me][ln];
      const float fg = gp[me][64+ln];
      const float gg = gp[me][128+ln];
      const float og = gp[me][192+ln];
      c_reg = fsig(fg)*c_reg + fsig(ig)*ftanh(gg);
      h_reg = fsig(og)*ftanh(c_reg);
    }
  }

  // ---- epilogue: loss reduce + prediction/BCE (chain waves) ----
  if (chain){
    float l = loss_acc;   // nonzero only on ln<32
    l += __shfl_xor(l,16); l += __shfl_xor(l,8);
    l += __shfl_xor(l,4);  l += __shfl_xor(l,2); l += __shfl_xor(l,1);
    if (ln == 0) atomicAdd(xl_acc, l);

    float p = h_reg * out_W[ln];
    p += __shfl_xor(p,32); p += __shfl_xor(p,16); p += __shfl_xor(p,8);
    p += __shfl_xor(p,4);  p += __shfl_xor(p,2);  p += __shfl_xor(p,1);
    if (ln == 0){
      const float y = p + out_b[0];
      predictions[b2] = fsig(y);
      const float lab = labels[b2];
      const float it  = is_train[b2];
      const float mx  = fmaxf(-y, 0.f);
      const float bce = y - y*lab + mx + __logf(__expf(-mx) + __expf(-y - mx));
      atomicAdd(bce_acc, bce * it);
    }
  }
}

// ---------------------------------------------------------------------------
// Kernel 3: finalize loss scalar
// ---------------------------------------------------------------------------
__global__ void final_kernel(const float* __restrict__ is_train,
                             const float* __restrict__ ws,
                             float* __restrict__ out){
  const int tid = threadIdx.x;
  __shared__ float red[256];
  red[tid] = is_train[tid] + is_train[tid+256] + is_train[tid+512] + is_train[tid+768];
  __syncthreads();
  for (int off = 128; off > 0; off >>= 1){
    if (tid < off) red[tid] += red[tid + off];
    __syncthreads();
  }
  if (tid == 0){
    const float yl = ws[1] / (red[0] + EPSF);
    out[0] = ws[0] / 256.0f + 0.1f * yl;
  }
}

extern "C" void kernel_launch(void* const* d_in, const int* in_sizes, int n_in,
                              void* d_out, int out_size, void* d_ws, size_t ws_size,
                              hipStream_t stream){
  const float* values   = (const float*)d_in[0];
  const float* masks    = (const float*)d_in[1];
  const float* deltas   = (const float*)d_in[2];
  const float* labels   = (const float*)d_in[5];
  const float* is_train = (const float*)d_in[6];
  const float* td_h_W   = (const float*)d_in[7];
  const float* td_h_b   = (const float*)d_in[8];
  const float* td_x_W   = (const float*)d_in[9];
  const float* td_x_b   = (const float*)d_in[10];
  const float* hist_W   = (const float*)d_in[11];
  const float* hist_b   = (const float*)d_in[12];
  const float* feat_W   = (const float*)d_in[13];
  const float* feat_b   = (const float*)d_in[14];
  const float* wc_W     = (const float*)d_in[15];
  const float* wc_b     = (const float*)d_in[16];
  const float* W_ih     = (const float*)d_in[17];
  const float* W_hh     = (const float*)d_in[18];
  const float* b_ih     = (const float*)d_in[19];
  const float* b_hh     = (const float*)d_in[20];
  const float* out_W    = (const float*)d_in[21];
  const float* out_b    = (const float*)d_in[22];

  float* out = (float*)d_out;                 // [0]=loss, [1..1025)=preds, [1025..)=imps
  float* ws  = (float*)d_ws;                  // [0]=xl_sum, [1]=bce_sum, [2..258)=msum

  hipMemsetAsync(ws, 0, 2*sizeof(float), stream);
  msum_kernel<<<256, 256, 0, stream>>>(masks, ws + 2);
  rits_kernel<<<256, 512, 0, stream>>>(values, masks, deltas, labels, is_train,
      td_h_W, td_h_b, td_x_W, td_x_b, hist_W, hist_b, feat_W, feat_b,
      wc_W, wc_b, W_ih, W_hh, b_ih, b_hh, out_W, out_b,
      ws + 2, ws + 0, ws + 1, out + 1, out + 1 + 1024);
  final_kernel<<<1, 256, 0, stream>>>(is_train, ws, out);
}